// Round 13
// baseline (1770.835 us; speedup 1.0000x reference)
//
#include <hip/hip_runtime.h>

// Problem constants
#define BB 64
#define TT 4
#define NOBJ 6
#define RTOT 1536   // B*T*N
#define DD 256

typedef unsigned short ushort_t;
typedef unsigned int uint_t;
typedef __attribute__((ext_vector_type(8))) short short8_t;   // 8 bf16 (4 VGPRs)
typedef __attribute__((ext_vector_type(4))) short short4_t;   // 4 bf16 (2 VGPRs)
typedef __attribute__((ext_vector_type(4))) unsigned int uint4_t;
typedef __attribute__((ext_vector_type(4))) float f32x4;

struct MatDesc { const float* src; float* dst; int kshift; int stride; int coff; };
struct MatDescs { MatDesc m[4]; };

#define FMA4(ACC, A4, W4) do { \
  ACC = fmaf((A4).x, (W4).x, ACC); \
  ACC = fmaf((A4).y, (W4).y, ACC); \
  ACC = fmaf((A4).z, (W4).z, ACC); \
  ACC = fmaf((A4).w, (W4).w, ACC); } while(0)

#define MFMA_BF16_16x16x32 __builtin_amdgcn_mfma_f32_16x16x32_bf16

// f1 LDS swizzle v2: XOR slot bits with (col>>1)&7 (2-way on both read and write sides).
#define F1IDX(row, col, ch) (((((row) * 34 + (col)) * 64) + (ch)) ^ (((((col) >> 1) & 7)) << 3))

__device__ __forceinline__ void split_bf16(float v, ushort_t& hs, ushort_t& ls) {
  unsigned int bits = __float_as_uint(v);
  hs = (ushort_t)(bits >> 16);
  float hf = __uint_as_float(bits & 0xFFFF0000u);
  ls = (ushort_t)(__float_as_uint(v - hf) >> 16);
}

// ---- prep: transpose weight mats into WT[kq][d][4] layout (fc0, fc1c, red) ----
__global__ void prep_mats(MatDescs md) {
  const MatDesc de = md.m[blockIdx.y];
  int K = 1 << de.kshift;
  int idx = blockIdx.x * 256 + threadIdx.x;
  if (idx >= (256 << de.kshift)) return;
  int d = idx >> de.kshift;
  int kk = idx & (K - 1);
  de.dst[(kk >> 2) * 1024 + d * 4 + (kk & 3)] = de.src[d * de.stride + de.coff + kk];
}

// ---- prep: w1 bf16 MFMA fragments, conv2 split-bf16 planes, rbuf, pair flags ----
__global__ void prep_small(const float* __restrict__ w1, const float* __restrict__ w2,
                           const float* __restrict__ rois,
                           ushort_t* __restrict__ w1bh, ushort_t* __restrict__ w1bl,
                           ushort_t* __restrict__ w2fh, ushort_t* __restrict__ w2fl,
                           float* __restrict__ rbuf, unsigned* __restrict__ flags) {
  int idx = blockIdx.x * 256 + threadIdx.x;
  if (idx < 2048) {
    int j = idx & 7, lane = (idx >> 3) & 63, ct = idx >> 9;
    int k = ((lane >> 4) << 3) + j;
    int co = ct * 16 + (lane & 15);
    float v = (k < 27) ? w1[co * 27 + k] : 0.f;
    ushort_t hs, ls;
    split_bf16(v, hs, ls);
    w1bh[idx] = hs; w1bl[idx] = ls;
  }
  int i2 = idx - 2048;
  if (i2 >= 0 && i2 < 36864) {
    int j = i2 & 7, lane = (i2 >> 3) & 63, nt = (i2 >> 9) & 3, q = (i2 >> 11) & 1, t = i2 >> 12;
    int co = nt * 16 + (lane & 15);
    int ci = q * 32 + ((lane >> 4) << 3) + j;
    ushort_t hs, ls;
    split_bf16(w2[(co * 64 + ci) * 9 + t], hs, ls);
    w2fh[i2] = hs; w2fl[i2] = ls;
  }
  int i3 = idx - 38912;
  if (i3 >= 0 && i3 < 384) {
    int b = i3 / 6, n = i3 % 6;
    float acc = 0.f;
    for (int t = 0; t < TT; t++) {
      const float* rp = rois + ((b * TT + t) * NOBJ + n) * 5;
      acc += (rp[4] - rp[2]) * 0.5f + (rp[3] - rp[1]) * 0.5f;
    }
    rbuf[i3] = acc * 0.125f;
  }
  int i4 = idx - 39296;
  if (i4 >= 0 && i4 < 128) flags[i4] = 0u;
}

// ---- prep rollout B-fragments (bf16 hi/lo) ----
// B1 per k:  [nt48][kq8][lane][8j]  (nt<16: self, 16..31: u, 32..47: v)
// Baff per k: [nt16][kq8][lane][8j]
// Bout per k: [nt16][kq16][lane][8j] (kin 0..511 over [a|s])
// Bagg per k: [nt16][kq8][lane][8j]  (kin_local 0..255, global kin = k*256+kin_local)
__global__ void prep_rollB(const float* __restrict__ g_self_w, const float* __restrict__ g_rel_w,
                           const float* __restrict__ g_aff_w, const float* __restrict__ g_out_w,
                           const float* __restrict__ agg_w,
                           ushort_t* __restrict__ b1h, ushort_t* __restrict__ b1l,
                           ushort_t* __restrict__ bafh, ushort_t* __restrict__ bafl,
                           ushort_t* __restrict__ bouh, ushort_t* __restrict__ boul,
                           ushort_t* __restrict__ bagh, ushort_t* __restrict__ bagl) {
  int idx = blockIdx.x * 256 + threadIdx.x;
  if (idx >= 1835008) return;
  ushort_t hs, ls;
  if (idx >= 1572864) {
    int r4 = idx - 1572864;   // 0..262143  bits: k(2)|nt(4)|kq(3)|lane(6)|j(3)
    int jj = r4 & 7, lane = (r4 >> 3) & 63, kq = (r4 >> 9) & 7, nt = (r4 >> 12) & 15;
    int kk = r4 >> 16;
    int kin = kq * 32 + ((lane >> 4) << 3) + jj;
    int d = nt * 16 + (lane & 15);
    split_bf16(agg_w[d * 1024 + kk * 256 + kin], hs, ls);
    bagh[r4] = hs; bagl[r4] = ls;
    return;
  }
  int k = idx / 393216;
  int r = idx - k * 393216;
  if (r < 196608) {
    int j = r & 7, lane = (r >> 3) & 63, kq = (r >> 9) & 7, nt = r >> 12;
    int kin = kq * 32 + ((lane >> 4) << 3) + j;
    int d = (nt & 15) * 16 + (lane & 15);
    int mat = nt >> 4;
    float v = (mat == 0) ? g_self_w[(k * 256 + d) * 256 + kin]
                         : g_rel_w[(k * 256 + d) * 512 + (mat == 2 ? 256 : 0) + kin];
    split_bf16(v, hs, ls);
    b1h[k * 196608 + r] = hs; b1l[k * 196608 + r] = ls;
  } else if (r < 262144) {
    int r2 = r - 196608;
    int j = r2 & 7, lane = (r2 >> 3) & 63, kq = (r2 >> 9) & 7, nt = r2 >> 12;
    int kin = kq * 32 + ((lane >> 4) << 3) + j;
    int d = nt * 16 + (lane & 15);
    split_bf16(g_aff_w[(k * 256 + d) * 256 + kin], hs, ls);
    bafh[k * 65536 + r2] = hs; bafl[k * 65536 + r2] = ls;
  } else {
    int r3 = r - 262144;
    int j = r3 & 7, lane = (r3 >> 3) & 63, kq = (r3 >> 9) & 15, nt = r3 >> 13;
    int kin = kq * 32 + ((lane >> 4) << 3) + j;
    int d = nt * 16 + (lane & 15);
    split_bf16(g_out_w[(k * 256 + d) * 512 + kin], hs, ls);
    bouh[k * 131072 + r3] = hs; boul[k * 131072 + r3] = ls;
  }
}

// ---- fused conv1 (split-bf16 MFMA implicit-im2col) + conv2 (split-bf16 MFMA) ----
__global__ __launch_bounds__(512, 6) void convmf_kernel(const float* __restrict__ x,
                                                        const ushort_t* __restrict__ w1bh,
                                                        const ushort_t* __restrict__ w1bl,
                                                        const float* __restrict__ b1,
                                                        const ushort_t* __restrict__ w2fh,
                                                        const ushort_t* __restrict__ w2fl,
                                                        const float* __restrict__ b2,
                                                        float* __restrict__ feat2) {
  __shared__ __align__(16) uint_t xshl[3 * 11 * 72];   // hi16 | lo16 packed
  __shared__ __align__(16) ushort_t f1h[5 * 34 * 64];
  __shared__ __align__(16) ushort_t f1l[5 * 34 * 64];
  int bx = blockIdx.x;
  int h = bx & 1;
  int band = (bx >> 1) & 15;
  int n = bx >> 5;
  int tid = threadIdx.x;
  int wave = __builtin_amdgcn_readfirstlane(tid >> 6);
  int lane = tid & 63;
  int m15 = lane & 15, quad = lane >> 4;

  for (int i = tid; i < 561; i += 512) {
    int ci = i / 187;             // 187 = 11*17
    int rem = i - ci * 187;
    int row = rem / 17;
    int c4 = rem - row * 17;
    int gr = 8 * band + row;
    float4 v = {0.f, 0.f, 0.f, 0.f};
    if (gr < 128 && (h == 0 || c4 < 16))
      v = *(const float4*)&x[((n * 3 + ci) * 128 + gr) * 128 + h * 64 + c4 * 4];
    float vv[4] = {v.x, v.y, v.z, v.w};
    uint4_t u;
    #pragma unroll
    for (int t = 0; t < 4; t++) {
      unsigned int bits = __float_as_uint(vv[t]);
      unsigned int hs = bits & 0xFFFF0000u;
      float hf = __uint_as_float(hs);
      unsigned int ls = __float_as_uint(vv[t] - hf) >> 16;
      u[t] = hs | ls;
    }
    int base = (ci * 11 + row) * 72 + c4 * 4;
    *(uint4_t*)&xshl[base] = u;
  }
  __syncthreads();

  auto conv1_tile = [&](int pt) {
    int r, c; bool pvalid;
    if (pt < 10) { r = pt >> 1; c = ((pt & 1) << 4) + m15; pvalid = true; }
    else { r = (m15 < 5) ? m15 : 0; c = 32; pvalid = (m15 < 5); }
    short8_t Xh = {}; short8_t Xl = {};
    #pragma unroll
    for (int j = 0; j < 8; j++) {
      int k = quad * 8 + j;
      int ci = (k * 57) >> 9;
      int rem = k - ci * 9;
      int ky = (rem * 11) >> 5;
      int kx = rem - ky * 3;
      int addr = (ci * 11 + 2 * r + ky) * 72 + 2 * c + kx;
      if (k < 27 && pvalid) {
        uint_t v = xshl[addr];
        Xh[j] = (short)(v >> 16);
        Xl[j] = (short)(v & 0xFFFFu);
      }
    }
    bool zf = (r == 4 && band == 15) || (c == 32 && h == 1);
    #pragma unroll
    for (int ct = 0; ct < 4; ct++) {
      short8_t Wh = *(const short8_t*)(w1bh + ((ct * 64 + lane) << 3));
      short8_t Wl = *(const short8_t*)(w1bl + ((ct * 64 + lane) << 3));
      f32x4 a1 = {0.f, 0.f, 0.f, 0.f};
      a1 = MFMA_BF16_16x16x32(Wh, Xh, a1, 0, 0, 0);
      a1 = MFMA_BF16_16x16x32(Wh, Xl, a1, 0, 0, 0);
      a1 = MFMA_BF16_16x16x32(Wl, Xh, a1, 0, 0, 0);
      if (pvalid) {
        short4_t hv, lv;
        #pragma unroll
        for (int reg = 0; reg < 4; reg++) {
          int co = ct * 16 + (quad << 2) + reg;
          float v = zf ? 0.f : fmaxf(a1[reg] + b1[co], 0.f);
          unsigned int bits = __float_as_uint(v);
          hv[reg] = (short)(bits >> 16);
          float hf = __uint_as_float(bits & 0xFFFF0000u);
          lv[reg] = (short)(__float_as_uint(v - hf) >> 16);
        }
        int be = F1IDX(r, c, ct * 16 + (quad << 2));
        *(short4_t*)&f1h[be] = hv;
        *(short4_t*)&f1l[be] = lv;
      }
    }
  };
  conv1_tile(wave);
  if (wave >= 4 && wave < 7) conv1_tile(8 + (wave - 4));
  __syncthreads();

  if (wave < 4) {
    int nt = wave;
    f32x4 acc0 = {0.f, 0.f, 0.f, 0.f};
    f32x4 acc1 = {0.f, 0.f, 0.f, 0.f};
    #pragma unroll
    for (int t = 0; t < 9; t++) {
      int ky = t / 3, kx = t % 3;
      int col = 2 * m15 + kx;
      #pragma unroll
      for (int q = 0; q < 2; q++) {
        int widx = (((t * 2 + q) * 4 + nt) * 64 + lane) * 8;
        short8_t Bh = *(const short8_t*)(w2fh + widx);
        short8_t Bl = *(const short8_t*)(w2fl + widx);
        {
          int ae = F1IDX(ky, col, q * 32 + (quad << 3));
          short8_t Ah = *(const short8_t*)&f1h[ae];
          short8_t Al = *(const short8_t*)&f1l[ae];
          acc0 = MFMA_BF16_16x16x32(Ah, Bh, acc0, 0, 0, 0);
          acc0 = MFMA_BF16_16x16x32(Ah, Bl, acc0, 0, 0, 0);
          acc0 = MFMA_BF16_16x16x32(Al, Bh, acc0, 0, 0, 0);
        }
        {
          int ae = F1IDX(2 + ky, col, q * 32 + (quad << 3));
          short8_t Ah = *(const short8_t*)&f1h[ae];
          short8_t Al = *(const short8_t*)&f1l[ae];
          acc1 = MFMA_BF16_16x16x32(Ah, Bh, acc1, 0, 0, 0);
          acc1 = MFMA_BF16_16x16x32(Ah, Bl, acc1, 0, 0, 0);
          acc1 = MFMA_BF16_16x16x32(Al, Bh, acc1, 0, 0, 0);
        }
      }
    }
    int co = nt * 16 + m15;
    float bv = b2[co];
    int ox = h * 16 + (quad << 2);
    {
      int oy = band * 2;
      float4 o;
      o.x = fmaxf(acc0[0] + bv, 0.f);
      o.y = fmaxf(acc0[1] + bv, 0.f);
      o.z = fmaxf(acc0[2] + bv, 0.f);
      o.w = fmaxf(acc0[3] + bv, 0.f);
      *(float4*)&feat2[((n * 64 + co) * 32 + oy) * 32 + ox] = o;
    }
    {
      int oy = band * 2 + 1;
      float4 o;
      o.x = fmaxf(acc1[0] + bv, 0.f);
      o.y = fmaxf(acc1[1] + bv, 0.f);
      o.z = fmaxf(acc1[2] + bv, 0.f);
      o.w = fmaxf(acc1[3] + bv, 0.f);
      *(float4*)&feat2[((n * 64 + co) * 32 + oy) * 32 + ox] = o;
    }
  }
}

// ---- fused ROI-align + fc0 GEMM (bilinear gather inline during As staging) ----
__global__ __launch_bounds__(512) void roigemm_kernel(const float* __restrict__ feat2,
                                                      const float* __restrict__ rois,
                                                      const float* __restrict__ WT,
                                                      const float* __restrict__ bias,
                                                      float* __restrict__ cat) {
  __shared__ __align__(16) float As[8 * 1024];
  int tid = threadIdx.x;
  int r0 = blockIdx.x * 8;
  for (int idx = tid; idx < 8192; idx += 512) {
    int px = idx & 3, py = (idx >> 2) & 3, c = (idx >> 4) & 63, rr = idx >> 10;
    const float* rp = rois + (size_t)(r0 + rr) * 5;
    int bi = (int)rp[0];
    float x1 = rp[1] * 0.25f, y1 = rp[2] * 0.25f, x2 = rp[3] * 0.25f, y2 = rp[4] * 0.25f;
    float bw = fmaxf(x2 - x1, 1.0f) * 0.25f;
    float bh = fmaxf(y2 - y1, 1.0f) * 0.25f;
    float sx = x1 + bw * (px + 0.5f);
    float sy = y1 + bh * (py + 0.5f);
    float x0f = fminf(fmaxf(floorf(sx), 0.f), 31.f);
    float y0f = fminf(fmaxf(floorf(sy), 0.f), 31.f);
    float lx = fminf(fmaxf(sx - x0f, 0.f), 1.f);
    float ly = fminf(fmaxf(sy - y0f, 0.f), 1.f);
    int ix0 = (int)x0f, iy0 = (int)y0f;
    int ix1 = min(ix0 + 1, 31), iy1 = min(iy0 + 1, 31);
    const float* f = feat2 + (bi * 64 + c) * 1024;
    float v00 = f[iy0 * 32 + ix0], v01 = f[iy0 * 32 + ix1];
    float v10 = f[iy1 * 32 + ix0], v11 = f[iy1 * 32 + ix1];
    As[idx] = v00 * (1 - ly) * (1 - lx) + v01 * (1 - ly) * lx + v10 * ly * (1 - lx) +
              v11 * ly * lx;
  }
  __syncthreads();
  int d = tid & 255;
  int half = __builtin_amdgcn_readfirstlane(tid >> 8);
  float acc[4] = {};
  const float* asb = As + half * 4 * 1024;
  for (int kq = 0; kq < 256; kq++) {
    float4 wv = *(const float4*)(WT + kq * 1024 + d * 4);
    #pragma unroll
    for (int rr = 0; rr < 4; rr++) {
      float4 a4 = *(const float4*)(asb + rr * 1024 + kq * 4);
      FMA4(acc[rr], a4, wv);
    }
  }
  float bv = bias[d];
  #pragma unroll
  for (int rr = 0; rr < 4; rr++)
    cat[(r0 + half * 4 + rr) * 512 + d] = fmaxf(acc[rr] + bv, 0.f);
}

// ---- generic broadcast-row GEMM + bias + relu ----
__global__ __launch_bounds__(512) void gemmB_kernel(const float* __restrict__ A, int lda,
                                                    const float* __restrict__ WT,
                                                    const float* __restrict__ bias,
                                                    float* __restrict__ C, int ldc, int coff,
                                                    int kshift) {
  __shared__ __align__(16) float As[8 * 1024];
  int K = 1 << kshift;
  int tid = threadIdx.x;
  int r0 = blockIdx.x * 8;
  for (int idx = tid; idx < 8 * K; idx += 512)
    As[idx] = A[(r0 + (idx >> kshift)) * lda + (idx & (K - 1))];
  __syncthreads();
  int d = tid & 255;
  int half = __builtin_amdgcn_readfirstlane(tid >> 8);
  float acc[4] = {};
  const float* asb = As + half * 4 * K;
  for (int kq = 0; kq < (K >> 2); kq++) {
    float4 wv = *(const float4*)(WT + kq * 1024 + d * 4);
    #pragma unroll
    for (int rr = 0; rr < 4; rr++) {
      float4 a4 = *(const float4*)(asb + rr * K + kq * 4);
      FMA4(acc[rr], a4, wv);
    }
  }
  float bv = bias[d];
  #pragma unroll
  for (int rr = 0; rr < 4; rr++)
    C[(r0 + half * 4 + rr) * ldc + coff + d] = fmaxf(acc[rr] + bv, 0.f);
}

// ---- fused emb(2->256 relu) + fc1c(256->256 relu) -> cat[:,256:] ----
__global__ __launch_bounds__(512) void embgemm_kernel(const float* __restrict__ src_coor,
                                                      const float* __restrict__ w0,
                                                      const float* __restrict__ b0,
                                                      const float* __restrict__ fc1cT,
                                                      const float* __restrict__ b1,
                                                      float* __restrict__ cat) {
  __shared__ __align__(16) float As[8 * 256];
  int tid = threadIdx.x;
  int r0 = blockIdx.x * 8;
  for (int idx = tid; idx < 2048; idx += 512) {
    int rr = idx >> 8, c = idx & 255;
    const float* cp = src_coor + (size_t)(r0 + rr) * 2;
    float v = cp[0] * w0[c * 2] + cp[1] * w0[c * 2 + 1] + b0[c];
    As[idx] = fmaxf(v, 0.f);
  }
  __syncthreads();
  int d = tid & 255;
  int half = __builtin_amdgcn_readfirstlane(tid >> 8);
  float acc[4] = {};
  const float* asb = As + half * 4 * 256;
  for (int kq = 0; kq < 64; kq++) {
    float4 wv = *(const float4*)(fc1cT + kq * 1024 + d * 4);
    #pragma unroll
    for (int rr = 0; rr < 4; rr++) {
      float4 a4 = *(const float4*)(asb + rr * 256 + kq * 4);
      FMA4(acc[rr], a4, wv);
    }
  }
  float bv = b1[d];
  #pragma unroll
  for (int rr = 0; rr < 4; rr++)
    cat[(r0 + half * 4 + rr) * 512 + 256 + d] = fmaxf(acc[rr] + bv, 0.f);
}

// ---- internet pair: rollouts {j0, j0+1} in ONE regular launch. ----
// Within-launch dep: only k==3 blocks at j0+1 need spart slot j0 (4 same-pb writers).
// First-rollout P5 -> atomicExch (coherence point) + fence + flag; reader spins flag,
// then coherence-point atomic loads. All other traffic plain (launch-boundary visibility).
// Regular launch (NOT cooperative: rounds 3/7 proved cooperative bypasses L2).
__global__ __launch_bounds__(1024, 4) void internet_pair(
    int j0, const float* __restrict__ obj, float* __restrict__ spart,
    const float* __restrict__ src_coor, float* __restrict__ dout,
    const float* __restrict__ rbuf, unsigned* __restrict__ flags,
    const ushort_t* __restrict__ b1h, const ushort_t* __restrict__ b1l,
    const ushort_t* __restrict__ bafh, const ushort_t* __restrict__ bafl,
    const ushort_t* __restrict__ bouh, const ushort_t* __restrict__ boul,
    const ushort_t* __restrict__ bagh, const ushort_t* __restrict__ bagl,
    const float* __restrict__ self_b, const float* __restrict__ rel_b,
    const float* __restrict__ aff_b, const float* __restrict__ out_b,
    const float* __restrict__ agg_b,
    const float* __restrict__ decw, const float* __restrict__ decb) {
  __shared__ __align__(16) char smem[62784];
  __shared__ float coor_lds[2][12], r_lds[2][6], mw[2][6][8];
  float* bufA = (float*)smem;
  ushort_t* sAh = (ushort_t*)(smem + 37440);
  ushort_t* sAl = (ushort_t*)(smem + 43776);
  ushort_t* hAh = (ushort_t*)(smem + 50112);
  ushort_t* hAl = (ushort_t*)(smem + 56448);
  ushort_t* aAh = (ushort_t*)(smem);
  ushort_t* aAl = (ushort_t*)(smem + 6336);
  ushort_t* csAh = hAh;
  ushort_t* csAl = hAl;

  int bx = blockIdx.x;
  int k = __builtin_amdgcn_readfirstlane((bx & 7) >> 1);
  int pb = __builtin_amdgcn_readfirstlane(((bx & 1) << 4) | (bx >> 3));   // 0..31
  int tid = threadIdx.x;
  int wave = __builtin_amdgcn_readfirstlane(tid >> 6);   // 0..15
  int lane = tid & 63;
  int m15 = lane & 15, quad = lane >> 4;
  int mrow = (m15 < 12) ? m15 : 0;
  unsigned* flag = &flags[(j0 >> 1) * 32 + pb];

  const ushort_t* b1hk = b1h + (size_t)k * 196608;
  const ushort_t* b1lk = b1l + (size_t)k * 196608;
  const ushort_t* bafhk = bafh + (size_t)k * 65536;
  const ushort_t* baflk = bafl + (size_t)k * 65536;
  const ushort_t* bouhk = bouh + (size_t)k * 131072;
  const ushort_t* boulk = boul + (size_t)k * 131072;
  const ushort_t* baghk = bagh + (size_t)k * 65536;
  const ushort_t* baglk = bagl + (size_t)k * 65536;

  if (tid < 12) r_lds[tid / 6][tid % 6] = rbuf[(pb * 2 + tid / 6) * 6 + tid % 6];

  for (int jj = j0; jj <= j0 + 1; ++jj) {
    int sl = jj + k;
    bool dodec = (k == 3) && (jj >= 1);
    bool second = (jj != j0);

    // acquire (second rollout, k==3 only): wait for the 4 same-pb writers of slot j0
    if (second) {
      if (k == 3 && tid == 0) {
        while (atomicAdd(flag, 0u) < 4u) __builtin_amdgcn_s_sleep(2);
      }
      __syncthreads();
    }
    bool atomRead = second && (k == 3);

    // prefetch P1 kq=0 B-fragments
    short8_t p1Bh[2][3], p1Bl[2][3];
    #pragma unroll
    for (int tt = 0; tt < 3; tt++) {
      int t = wave * 3 + tt;
      int bi = ((t * 8 + 0) * 64 + lane) * 8;
      p1Bh[0][tt] = *(const short8_t*)(b1hk + bi);
      p1Bl[0][tt] = *(const short8_t*)(b1lk + bi);
    }

    // P0a: coor / stage s (12x256): fp32 -> bufA[0..3071], bf16 split -> sA
    if (!dodec && tid < 24) {
      int bq = tid / 12, t12 = tid % 12;
      int i = t12 >> 1, c = t12 & 1;
      int b = pb * 2 + bq;
      coor_lds[bq][t12] = (sl < 4) ? src_coor[((b * 4 + sl) * 6 + i) * 2 + c]
                                   : dout[((b * 8 + (sl - 4)) * 6 + i) * 4 + 2 + c];
    }
    {
      size_t pbase = ((size_t)(sl - 4) * 4) * 64;
      for (int pos = tid; pos < 3072; pos += 1024) {
        int row = pos >> 8, d = pos & 255;
        int bq = row >= 6, i = row - bq * 6;
        int b = pb * 2 + bq;
        float v;
        if (sl < 4) {
          v = obj[(b * 4 + sl) * 1536 + i * 256 + d];
        } else {
          size_t eo = (size_t)i * 256 + d;
          float* p0 = &spart[(pbase +   0 + b) * 1536 + eo];
          float* p1 = &spart[(pbase +  64 + b) * 1536 + eo];
          float* p2 = &spart[(pbase + 128 + b) * 1536 + eo];
          float* p3 = &spart[(pbase + 192 + b) * 1536 + eo];
          if (atomRead) {
            v = agg_b[d] + atomicAdd(p0, 0.f) + atomicAdd(p1, 0.f) +
                atomicAdd(p2, 0.f) + atomicAdd(p3, 0.f);
          } else {
            v = agg_b[d] + *p0 + *p1 + *p2 + *p3;
          }
        }
        bufA[pos] = v;
        ushort_t hs, ls;
        split_bf16(v, hs, ls);
        sAh[row * 264 + d] = hs;
        sAl[row * 264 + d] = ls;
      }
    }
    __syncthreads();

    // P0b: dec for rollout jj-1 (k==3), reading fp32 s from bufA
    if (dodec && tid < 384) {
      int lane8 = tid & 7, p = tid >> 3;   // 0..47
      int bq = p / 24, pp = p % 24, i = pp >> 2, o = pp & 3;
      float a2 = 0.f;
      #pragma unroll
      for (int m = 0; m < 32; m++) {
        int dd = lane8 + m * 8;
        a2 = fmaf(bufA[(bq * 6 + i) * 256 + dd], decw[o * 256 + dd], a2);
      }
      a2 += __shfl_down(a2, 4, 8);
      a2 += __shfl_down(a2, 2, 8);
      a2 += __shfl_down(a2, 1, 8);
      if (lane8 == 0) {
        float val = a2 + decb[o];
        int b = pb * 2 + bq;
        dout[((b * 8 + (jj - 1)) * 6 + i) * 4 + o] = val;
        if (o >= 2) coor_lds[bq][i * 2 + (o - 2)] = val;
      }
    }
    __syncthreads();

    // P1: mask + stage-1 MFMA (48 tiles, 3/wave) with 2-deep B ring
    #pragma unroll
    for (int tt = 0; tt < 3; tt++) {
      int t = wave * 3 + tt;
      int bi = ((t * 8 + 1) * 64 + lane) * 8;
      p1Bh[1][tt] = *(const short8_t*)(b1hk + bi);
      p1Bl[1][tt] = *(const short8_t*)(b1lk + bi);
    }
    if (tid < 72) {
      int bq = tid / 36, rest = tid % 36;
      int i = rest / 6, jx = rest % 6;
      float dx = coor_lds[bq][i * 2] - coor_lds[bq][jx * 2];
      float dy = coor_lds[bq][i * 2 + 1] - coor_lds[bq][jx * 2 + 1];
      float dist = sqrtf(dx * dx + dy * dy);
      mw[bq][i][jx] = (i != jx && dist <= r_lds[bq][i] + r_lds[bq][jx]) ? 1.f : 0.f;
    }
    {
      f32x4 acc1[3] = {};
      #pragma unroll
      for (int kq = 0; kq < 8; kq++) {
        int cur = kq & 1;
        int aoff = mrow * 264 + kq * 32 + quad * 8;
        short8_t Ah = *(const short8_t*)(sAh + aoff);
        short8_t Al = *(const short8_t*)(sAl + aoff);
        #pragma unroll
        for (int tt = 0; tt < 3; tt++) {
          acc1[tt] = MFMA_BF16_16x16x32(Ah, p1Bh[cur][tt], acc1[tt], 0, 0, 0);
          acc1[tt] = MFMA_BF16_16x16x32(Ah, p1Bl[cur][tt], acc1[tt], 0, 0, 0);
          acc1[tt] = MFMA_BF16_16x16x32(Al, p1Bh[cur][tt], acc1[tt], 0, 0, 0);
        }
        if (kq < 6) {
          #pragma unroll
          for (int tt = 0; tt < 3; tt++) {
            int t = wave * 3 + tt;
            int bi = ((t * 8 + kq + 2) * 64 + lane) * 8;
            p1Bh[cur][tt] = *(const short8_t*)(b1hk + bi);
            p1Bl[cur][tt] = *(const short8_t*)(b1lk + bi);
          }
        }
      }
      #pragma unroll
      for (int tt = 0; tt < 3; tt++) {
        int t = wave * 3 + tt;
        int mat = t >> 4, ntm = t & 15;
        float* buf = bufA + mat * 3120;
        #pragma unroll
        for (int reg = 0; reg < 4; reg++) {
          int m = quad * 4 + reg;
          if (m < 12) buf[m * 260 + ntm * 16 + m15] = acc1[tt][reg];
        }
      }
    }
    __syncthreads();

    // P2: h = as + self_b + cnt*(au+rel_b) + sum_j mw*av ; repack -> hA
    for (int pos = tid; pos < 3072; pos += 1024) {
      int row = pos >> 8, d = pos & 255;
      int bq = row >= 6, i = row - bq * 6;
      float as = bufA[row * 260 + d];
      float au = bufA[3120 + row * 260 + d];
      float cw = mw[bq][i][0] + mw[bq][i][1] + mw[bq][i][2] + mw[bq][i][3] + mw[bq][i][4] +
                 mw[bq][i][5];
      float hsum = as + self_b[k * 256 + d] + cw * (au + rel_b[k * 256 + d]);
      #pragma unroll
      for (int jx = 0; jx < 6; jx++)
        hsum = fmaf(mw[bq][i][jx], bufA[6240 + (bq * 6 + jx) * 260 + d], hsum);
      ushort_t hs, ls;
      split_bf16(hsum, hs, ls);
      hAh[row * 264 + d] = hs;
      hAl[row * 264 + d] = ls;
    }
    // prefetch P3 kq 0..3: land during the barrier drain
    short8_t p3Bh[4], p3Bl[4];
    #pragma unroll
    for (int kq = 0; kq < 4; kq++) {
      int bi = ((wave * 8 + kq) * 64 + lane) * 8;
      p3Bh[kq] = *(const short8_t*)(bafhk + bi);
      p3Bl[kq] = *(const short8_t*)(baflk + bi);
    }
    __syncthreads();

    // P3: aff MFMA (16 tiles, 1/wave) -> relu -> aA (aliased over bufA)
    short8_t p4Bh[4], p4Bl[4];
    {
      short8_t r3h[2], r3l[2];
      #pragma unroll
      for (int q = 0; q < 2; q++) {
        int bi = ((wave * 8 + 4 + q) * 64 + lane) * 8;
        r3h[q] = *(const short8_t*)(bafhk + bi);
        r3l[q] = *(const short8_t*)(baflk + bi);
      }
      f32x4 acc2 = {0.f, 0.f, 0.f, 0.f};
      #pragma unroll
      for (int kq = 0; kq < 4; kq++) {
        int aoff = mrow * 264 + kq * 32 + quad * 8;
        short8_t Ah = *(const short8_t*)(hAh + aoff);
        short8_t Al = *(const short8_t*)(hAl + aoff);
        acc2 = MFMA_BF16_16x16x32(Ah, p3Bh[kq], acc2, 0, 0, 0);
        acc2 = MFMA_BF16_16x16x32(Ah, p3Bl[kq], acc2, 0, 0, 0);
        acc2 = MFMA_BF16_16x16x32(Al, p3Bh[kq], acc2, 0, 0, 0);
      }
      #pragma unroll
      for (int kq = 4; kq < 8; kq++) {
        int cur = kq & 1;
        int aoff = mrow * 264 + kq * 32 + quad * 8;
        short8_t Ah = *(const short8_t*)(hAh + aoff);
        short8_t Al = *(const short8_t*)(hAl + aoff);
        acc2 = MFMA_BF16_16x16x32(Ah, r3h[cur], acc2, 0, 0, 0);
        acc2 = MFMA_BF16_16x16x32(Ah, r3l[cur], acc2, 0, 0, 0);
        acc2 = MFMA_BF16_16x16x32(Al, r3h[cur], acc2, 0, 0, 0);
        if (kq < 6) {
          int bi = ((wave * 8 + kq + 2) * 64 + lane) * 8;
          r3h[cur] = *(const short8_t*)(bafhk + bi);
          r3l[cur] = *(const short8_t*)(baflk + bi);
        }
      }
      #pragma unroll
      for (int kq = 0; kq < 4; kq++) {
        int bi = ((wave * 16 + kq) * 64 + lane) * 8;
        p4Bh[kq] = *(const short8_t*)(bouhk + bi);
        p4Bl[kq] = *(const short8_t*)(boulk + bi);
      }
      __syncthreads();   // bufA fully read in P2; safe to overwrite with aA
      int d = wave * 16 + m15;
      float bias = aff_b[k * 256 + d];
      #pragma unroll
      for (int reg = 0; reg < 4; reg++) {
        int m = quad * 4 + reg;
        if (m < 12) {
          float v = fmaxf(acc2[reg] + bias, 0.f);
          ushort_t hs, ls;
          split_bf16(v, hs, ls);
          aAh[m * 264 + d] = hs;
          aAl[m * 264 + d] = ls;
        }
      }
    }
    __syncthreads();

    // P4: out MFMA over K=512 -> relu -> csA (LDS k-slice of cs)
    short8_t p5Bh[4], p5Bl[4];
    {
      short8_t r4h[2], r4l[2];
      #pragma unroll
      for (int q = 0; q < 2; q++) {
        int bi = ((wave * 16 + 4 + q) * 64 + lane) * 8;
        r4h[q] = *(const short8_t*)(bouhk + bi);
        r4l[q] = *(const short8_t*)(boulk + bi);
      }
      f32x4 acc3 = {0.f, 0.f, 0.f, 0.f};
      #pragma unroll
      for (int kq = 0; kq < 4; kq++) {
        const ushort_t* Abh = aAh + mrow * 264 + kq * 32;
        const ushort_t* Abl = aAl + mrow * 264 + kq * 32;
        short8_t Ah = *(const short8_t*)(Abh + quad * 8);
        short8_t Al = *(const short8_t*)(Abl + quad * 8);
        acc3 = MFMA_BF16_16x16x32(Ah, p4Bh[kq], acc3, 0, 0, 0);
        acc3 = MFMA_BF16_16x16x32(Ah, p4Bl[kq], acc3, 0, 0, 0);
        acc3 = MFMA_BF16_16x16x32(Al, p4Bh[kq], acc3, 0, 0, 0);
      }
      #pragma unroll
      for (int kq = 4; kq < 16; kq++) {
        int cur = kq & 1;
        const ushort_t* Abh = (kq < 8) ? (aAh + mrow * 264 + kq * 32)
                                       : (sAh + mrow * 264 + (kq - 8) * 32);
        const ushort_t* Abl = (kq < 8) ? (aAl + mrow * 264 + kq * 32)
                                       : (sAl + mrow * 264 + (kq - 8) * 32);
        short8_t Ah = *(const short8_t*)(Abh + quad * 8);
        short8_t Al = *(const short8_t*)(Abl + quad * 8);
        acc3 = MFMA_BF16_16x16x32(Ah, r4h[cur], acc3, 0, 0, 0);
        acc3 = MFMA_BF16_16x16x32(Ah, r4l[cur], acc3, 0, 0, 0);
        acc3 = MFMA_BF16_16x16x32(Al, r4h[cur], acc3, 0, 0, 0);
        if (kq < 14) {
          int bi = ((wave * 16 + kq + 2) * 64 + lane) * 8;
          r4h[cur] = *(const short8_t*)(bouhk + bi);
          r4l[cur] = *(const short8_t*)(boulk + bi);
        }
      }
      #pragma unroll
      for (int kq = 0; kq < 4; kq++) {
        int bi = ((wave * 8 + kq) * 64 + lane) * 8;
        p5Bh[kq] = *(const short8_t*)(baghk + bi);
        p5Bl[kq] = *(const short8_t*)(baglk + bi);
      }
      // hA dead after P3 -> write relu'd cs k-slice there (P4 reads only aA/sA).
      int d = wave * 16 + m15;
      float bias = out_b[k * 256 + d];
      #pragma unroll
      for (int reg = 0; reg < 4; reg++) {
        int m = quad * 4 + reg;
        if (m < 12) {
          float v = fmaxf(acc3[reg] + bias, 0.f);
          ushort_t hs, ls;
          split_bf16(v, hs, ls);
          csAh[m * 264 + d] = hs;
          csAl[m * 264 + d] = ls;
        }
      }
    }
    __syncthreads();

    // P5: partial agg spart[jj][k][b] (M=12,N=256,K=256)
    {
      short8_t r5h[2], r5l[2];
      #pragma unroll
      for (int q = 0; q < 2; q++) {
        int bi = ((wave * 8 + 4 + q) * 64 + lane) * 8;
        r5h[q] = *(const short8_t*)(baghk + bi);
        r5l[q] = *(const short8_t*)(baglk + bi);
      }
      f32x4 pacc = {0.f, 0.f, 0.f, 0.f};
      #pragma unroll
      for (int kq = 0; kq < 4; kq++) {
        int aoff = mrow * 264 + kq * 32 + quad * 8;
        short8_t Ah = *(const short8_t*)(csAh + aoff);
        short8_t Al = *(const short8_t*)(csAl + aoff);
        pacc = MFMA_BF16_16x16x32(Ah, p5Bh[kq], pacc, 0, 0, 0);
        pacc = MFMA_BF16_16x16x32(Ah, p5Bl[kq], pacc, 0, 0, 0);
        pacc = MFMA_BF16_16x16x32(Al, p5Bh[kq], pacc, 0, 0, 0);
      }
      #pragma unroll
      for (int kq = 4; kq < 8; kq++) {
        int cur = kq & 1;
        int aoff = mrow * 264 + kq * 32 + quad * 8;
        short8_t Ah = *(const short8_t*)(csAh + aoff);
        short8_t Al = *(const short8_t*)(csAl + aoff);
        pacc = MFMA_BF16_16x16x32(Ah, r5h[cur], pacc, 0, 0, 0);
        pacc = MFMA_BF16_16x16x32(Ah, r5l[cur], pacc, 0, 0, 0);
        pacc = MFMA_BF16_16x16x32(Al, r5h[cur], pacc, 0, 0, 0);
        if (kq < 6) {
          int bi = ((wave * 8 + kq + 2) * 64 + lane) * 8;
          r5h[cur] = *(const short8_t*)(baghk + bi);
          r5l[cur] = *(const short8_t*)(baglk + bi);
        }
      }
      int d = wave * 16 + m15;
      #pragma unroll
      for (int reg = 0; reg < 4; reg++) {
        int m = quad * 4 + reg;
        if (m < 12) {
          int bq = m >= 6, i = m - bq * 6;
          int b = pb * 2 + bq;
          float* dst = &spart[(((size_t)jj * 4 + k) * 64 + b) * 1536 + i * 256 + d];
          if (!second) atomicExch(dst, pacc[reg]);   // slot j0: read within this launch
          else *dst = pacc[reg];                     // slot j0+1: read next launch
        }
      }
    }

    // release (first rollout): slot j0 data at coherence point -> raise flag
    if (!second) {
      __threadfence();
      __syncthreads();
      if (tid == 0) atomicAdd(flag, 1u);
    }
  }
}

// ---- final dec for rollout 7 (sums the 4 agg partials + agg_b) ----
__global__ void dec_last(const float* __restrict__ spart, const float* __restrict__ agg_b,
                         const float* __restrict__ decw, const float* __restrict__ decb,
                         float* __restrict__ dout) {
  int b = blockIdx.x;
  int tid = threadIdx.x;   // 384
  int lane16 = tid & 15;
  int p = tid >> 4;
  int i = p >> 2, o = p & 3;
  const float* p0 = spart + ((size_t)(7 * 4 + 0) * 64 + b) * 1536 + i * 256;
  const float* p1 = spart + ((size_t)(7 * 4 + 1) * 64 + b) * 1536 + i * 256;
  const float* p2 = spart + ((size_t)(7 * 4 + 2) * 64 + b) * 1536 + i * 256;
  const float* p3 = spart + ((size_t)(7 * 4 + 3) * 64 + b) * 1536 + i * 256;
  float a2 = 0.f;
  #pragma unroll
  for (int m = 0; m < 16; m++) {
    int dd = lane16 + m * 16;
    float sv = agg_b[dd] + p0[dd] + p1[dd] + p2[dd] + p3[dd];
    a2 = fmaf(sv, decw[o * 256 + dd], a2);
  }
  a2 += __shfl_down(a2, 8, 16);
  a2 += __shfl_down(a2, 4, 16);
  a2 += __shfl_down(a2, 2, 16);
  a2 += __shfl_down(a2, 1, 16);
  if (lane16 == 0) dout[((b * 8 + 7) * 6 + i) * 4 + o] = a2 + decb[o];
}

extern "C" void kernel_launch(void* const* d_in, const int* in_sizes, int n_in,
                              void* d_out, int out_size, void* d_ws, size_t ws_size,
                              hipStream_t stream) {
  const float* x        = (const float*)d_in[0];
  const float* rois     = (const float*)d_in[1];
  const float* src_coor = (const float*)d_in[2];
  const float* w_conv1  = (const float*)d_in[3];
  const float* b_conv1  = (const float*)d_in[4];
  const float* w_conv2  = (const float*)d_in[5];
  const float* b_conv2  = (const float*)d_in[6];
  const float* fc0_w    = (const float*)d_in[7];
  const float* fc0_b    = (const float*)d_in[8];
  const float* fc0c_w   = (const float*)d_in[9];
  const float* fc0c_b   = (const float*)d_in[10];
  const float* fc1c_w   = (const float*)d_in[11];
  const float* fc1c_b   = (const float*)d_in[12];
  const float* red_w    = (const float*)d_in[13];
  const float* red_b    = (const float*)d_in[14];
  const float* g_self_w = (const float*)d_in[15];
  const float* g_self_b = (const float*)d_in[16];
  const float* g_rel_w  = (const float*)d_in[17];
  const float* g_rel_b  = (const float*)d_in[18];
  const float* g_aff_w  = (const float*)d_in[19];
  const float* g_aff_b  = (const float*)d_in[20];
  const float* g_out_w  = (const float*)d_in[21];
  const float* g_out_b  = (const float*)d_in[22];
  const float* agg_w    = (const float*)d_in[23];
  const float* agg_b    = (const float*)d_in[24];
  const float* dec_w    = (const float*)d_in[25];
  const float* dec_b    = (const float*)d_in[26];
  float* out = (float*)d_out;

  float* ws = (float*)d_ws;
  size_t off = 0;
  auto alloc = [&](size_t nf) { float* p = ws + off; off += (nf + 63) & ~(size_t)63; return p; };
  float* feat2 = alloc(16777216);   // (256,64,32,32)
  float* cat   = alloc(786432);
  float* obj   = alloc(393216);
  float* spart = alloc(3145728);    // [8 slots][4 k][64 b][6][256] agg partials
  float* rbuf  = alloc(384);
  unsigned* flags = (unsigned*)alloc(128);   // 4 pairs x 32 pb
  float* fc0T  = alloc(262144);
  float* fc1cT = alloc(65536);
  float* redT  = alloc(131072);
  ushort_t* w1bh = (ushort_t*)alloc(1024);
  ushort_t* w1bl = (ushort_t*)alloc(1024);
  ushort_t* w2fh = (ushort_t*)alloc(18432);
  ushort_t* w2fl = (ushort_t*)alloc(18432);
  ushort_t* b1h  = (ushort_t*)alloc(393216);   // 4k x 196608 shorts
  ushort_t* b1l  = (ushort_t*)alloc(393216);
  ushort_t* bafh = (ushort_t*)alloc(131072);   // 4k x 65536 shorts
  ushort_t* bafl = (ushort_t*)alloc(131072);
  ushort_t* bouh = (ushort_t*)alloc(262144);   // 4k x 131072 shorts
  ushort_t* boul = (ushort_t*)alloc(262144);
  ushort_t* bagh = (ushort_t*)alloc(131072);   // 4k x 65536 shorts (per-k agg slices)
  ushort_t* bagl = (ushort_t*)alloc(131072);

  MatDescs md;
  md.m[0] = {fc0_w,  fc0T,  10, 1024, 0};
  md.m[1] = {fc1c_w, fc1cT, 8,  256,  0};
  md.m[2] = {red_w,  redT,  9,  512,  0};
  md.m[3] = {red_w,  redT,  9,  512,  0};   // unused (grid.y = 3)

  prep_mats<<<dim3(1024, 3), dim3(256), 0, stream>>>(md);
  prep_small<<<dim3(154), dim3(256), 0, stream>>>(w_conv1, w_conv2, rois, w1bh, w1bl,
                                                  w2fh, w2fl, rbuf, flags);
  prep_rollB<<<dim3(7168), dim3(256), 0, stream>>>(g_self_w, g_rel_w, g_aff_w, g_out_w, agg_w,
                                                   b1h, b1l, bafh, bafl, bouh, boul, bagh, bagl);
  convmf_kernel<<<dim3(8192), dim3(512), 0, stream>>>(x, w1bh, w1bl, b_conv1, w2fh, w2fl,
                                                      b_conv2, feat2);
  roigemm_kernel<<<dim3(192), dim3(512), 0, stream>>>(feat2, rois, fc0T, fc0_b, cat);
  embgemm_kernel<<<dim3(192), dim3(512), 0, stream>>>(src_coor, fc0c_w, fc0c_b, fc1cT, fc1c_b, cat);
  gemmB_kernel<<<dim3(192), dim3(512), 0, stream>>>(cat, 512, redT, red_b, obj, 256, 0, 9);

  for (int p = 0; p < 4; p++) {
    internet_pair<<<dim3(128), dim3(1024), 0, stream>>>(2 * p, obj, spart, src_coor, out, rbuf,
        flags, b1h, b1l, bafh, bafl, bouh, boul, bagh, bagl,
        g_self_b, g_rel_b, g_aff_b, g_out_b, agg_b, dec_w, dec_b);
  }
  dec_last<<<dim3(64), dim3(384), 0, stream>>>(spart, agg_b, dec_w, dec_b, out);

  (void)in_sizes; (void)n_in; (void)out_size; (void)ws_size;
}

// Round 14
// 518.225 us; speedup vs baseline: 3.4171x; 3.4171x over previous
//
#include <hip/hip_runtime.h>

// Problem constants
#define BB 64
#define TT 4
#define NOBJ 6
#define RTOT 1536   // B*T*N
#define DD 256

typedef unsigned short ushort_t;
typedef unsigned int uint_t;
typedef __attribute__((ext_vector_type(8))) short short8_t;   // 8 bf16 (4 VGPRs)
typedef __attribute__((ext_vector_type(4))) short short4_t;   // 4 bf16 (2 VGPRs)
typedef __attribute__((ext_vector_type(4))) unsigned int uint4_t;
typedef __attribute__((ext_vector_type(4))) float f32x4;

struct MatDesc { const float* src; float* dst; int kshift; int stride; int coff; };
struct MatDescs { MatDesc m[4]; };

#define FMA4(ACC, A4, W4) do { \
  ACC = fmaf((A4).x, (W4).x, ACC); \
  ACC = fmaf((A4).y, (W4).y, ACC); \
  ACC = fmaf((A4).z, (W4).z, ACC); \
  ACC = fmaf((A4).w, (W4).w, ACC); } while(0)

#define MFMA_BF16_16x16x32 __builtin_amdgcn_mfma_f32_16x16x32_bf16

// f1 LDS swizzle v2: XOR slot bits with (col>>1)&7 (2-way on both read and write sides).
#define F1IDX(row, col, ch) (((((row) * 34 + (col)) * 64) + (ch)) ^ (((((col) >> 1) & 7)) << 3))

__device__ __forceinline__ void split_bf16(float v, ushort_t& hs, ushort_t& ls) {
  unsigned int bits = __float_as_uint(v);
  hs = (ushort_t)(bits >> 16);
  float hf = __uint_as_float(bits & 0xFFFF0000u);
  ls = (ushort_t)(__float_as_uint(v - hf) >> 16);
}

// ---- prep: w1 bf16 MFMA fragments, conv2 split-bf16 planes, rbuf ----
__global__ void prep_small(const float* __restrict__ w1, const float* __restrict__ w2,
                           const float* __restrict__ rois,
                           ushort_t* __restrict__ w1bh, ushort_t* __restrict__ w1bl,
                           ushort_t* __restrict__ w2fh, ushort_t* __restrict__ w2fl,
                           float* __restrict__ rbuf) {
  int idx = blockIdx.x * 256 + threadIdx.x;
  if (idx < 2048) {
    int j = idx & 7, lane = (idx >> 3) & 63, ct = idx >> 9;
    int k = ((lane >> 4) << 3) + j;
    int co = ct * 16 + (lane & 15);
    float v = (k < 27) ? w1[co * 27 + k] : 0.f;
    ushort_t hs, ls;
    split_bf16(v, hs, ls);
    w1bh[idx] = hs; w1bl[idx] = ls;
  }
  int i2 = idx - 2048;
  if (i2 >= 0 && i2 < 36864) {
    int j = i2 & 7, lane = (i2 >> 3) & 63, nt = (i2 >> 9) & 3, q = (i2 >> 11) & 1, t = i2 >> 12;
    int co = nt * 16 + (lane & 15);
    int ci = q * 32 + ((lane >> 4) << 3) + j;
    ushort_t hs, ls;
    split_bf16(w2[(co * 64 + ci) * 9 + t], hs, ls);
    w2fh[i2] = hs; w2fl[i2] = ls;
  }
  int i3 = idx - 38912;
  if (i3 >= 0 && i3 < 384) {
    int b = i3 / 6, n = i3 % 6;
    float acc = 0.f;
    for (int t = 0; t < TT; t++) {
      const float* rp = rois + ((b * TT + t) * NOBJ + n) * 5;
      acc += (rp[4] - rp[2]) * 0.5f + (rp[3] - rp[1]) * 0.5f;
    }
    rbuf[i3] = acc * 0.125f;
  }
}

// ---- mega launch: convmf (bx<8192) + prep_rollB (3584 blocks) + prep_mats (896 blocks) ----
// conv blocks dispatch first (critical path); prep blocks fill the tail drain.
__global__ __launch_bounds__(512, 6) void convprep_kernel(
    const float* __restrict__ x,
    const ushort_t* __restrict__ w1bh, const ushort_t* __restrict__ w1bl,
    const float* __restrict__ b1,
    const ushort_t* __restrict__ w2fh, const ushort_t* __restrict__ w2fl,
    const float* __restrict__ b2, float* __restrict__ feat2,
    const float* __restrict__ g_self_w, const float* __restrict__ g_rel_w,
    const float* __restrict__ g_aff_w, const float* __restrict__ g_out_w,
    const float* __restrict__ agg_w,
    ushort_t* __restrict__ b1h, ushort_t* __restrict__ b1l,
    ushort_t* __restrict__ bafh, ushort_t* __restrict__ bafl,
    ushort_t* __restrict__ bouh, ushort_t* __restrict__ boul,
    ushort_t* __restrict__ bagh, ushort_t* __restrict__ bagl,
    MatDescs md) {
  int bx = blockIdx.x;
  int tid = threadIdx.x;

  if (bx >= 8192) {
    ushort_t hs, ls;
    if (bx < 11776) {
      // prep_rollB: idx over [0, 1835008)
      int idx = (bx - 8192) * 512 + tid;
      if (idx >= 1572864) {
        int r4 = idx - 1572864;   // bits: k(2)|nt(4)|kq(3)|lane(6)|j(3)
        int jj = r4 & 7, lane = (r4 >> 3) & 63, kq = (r4 >> 9) & 7, nt = (r4 >> 12) & 15;
        int kk = r4 >> 16;
        int kin = kq * 32 + ((lane >> 4) << 3) + jj;
        int d = nt * 16 + (lane & 15);
        split_bf16(agg_w[d * 1024 + kk * 256 + kin], hs, ls);
        bagh[r4] = hs; bagl[r4] = ls;
        return;
      }
      int k = idx / 393216;
      int r = idx - k * 393216;
      if (r < 196608) {
        int j = r & 7, lane = (r >> 3) & 63, kq = (r >> 9) & 7, nt = r >> 12;
        int kin = kq * 32 + ((lane >> 4) << 3) + j;
        int d = (nt & 15) * 16 + (lane & 15);
        int mat = nt >> 4;
        float v = (mat == 0) ? g_self_w[(k * 256 + d) * 256 + kin]
                             : g_rel_w[(k * 256 + d) * 512 + (mat == 2 ? 256 : 0) + kin];
        split_bf16(v, hs, ls);
        b1h[k * 196608 + r] = hs; b1l[k * 196608 + r] = ls;
      } else if (r < 262144) {
        int r2 = r - 196608;
        int j = r2 & 7, lane = (r2 >> 3) & 63, kq = (r2 >> 9) & 7, nt = r2 >> 12;
        int kin = kq * 32 + ((lane >> 4) << 3) + j;
        int d = nt * 16 + (lane & 15);
        split_bf16(g_aff_w[(k * 256 + d) * 256 + kin], hs, ls);
        bafh[k * 65536 + r2] = hs; bafl[k * 65536 + r2] = ls;
      } else {
        int r3 = r - 262144;
        int j = r3 & 7, lane = (r3 >> 3) & 63, kq = (r3 >> 9) & 15, nt = r3 >> 13;
        int kin = kq * 32 + ((lane >> 4) << 3) + j;
        int d = nt * 16 + (lane & 15);
        split_bf16(g_out_w[(k * 256 + d) * 512 + kin], hs, ls);
        bouh[k * 131072 + r3] = hs; boul[k * 131072 + r3] = ls;
      }
      return;
    }
    // prep_mats: flattened [fc0T 262144 | fc1cT 65536 | redT 131072)
    int idx = (bx - 11776) * 512 + tid;
    int mi, local;
    if (idx < 262144) { mi = 0; local = idx; }
    else if (idx < 327680) { mi = 1; local = idx - 262144; }
    else { mi = 2; local = idx - 327680; }
    const MatDesc de = md.m[mi];
    int K = 1 << de.kshift;
    int d = local >> de.kshift;
    int kk = local & (K - 1);
    de.dst[(kk >> 2) * 1024 + d * 4 + (kk & 3)] = de.src[d * de.stride + de.coff + kk];
    return;
  }

  // ---- convmf body (round-12 verbatim) ----
  __shared__ __align__(16) uint_t xshl[3 * 11 * 72];   // hi16 | lo16 packed
  __shared__ __align__(16) ushort_t f1h[5 * 34 * 64];
  __shared__ __align__(16) ushort_t f1l[5 * 34 * 64];
  int h = bx & 1;
  int band = (bx >> 1) & 15;
  int n = bx >> 5;
  int wave = __builtin_amdgcn_readfirstlane(tid >> 6);
  int lane = tid & 63;
  int m15 = lane & 15, quad = lane >> 4;

  for (int i = tid; i < 561; i += 512) {
    int ci = i / 187;             // 187 = 11*17
    int rem = i - ci * 187;
    int row = rem / 17;
    int c4 = rem - row * 17;
    int gr = 8 * band + row;
    float4 v = {0.f, 0.f, 0.f, 0.f};
    if (gr < 128 && (h == 0 || c4 < 16))
      v = *(const float4*)&x[((n * 3 + ci) * 128 + gr) * 128 + h * 64 + c4 * 4];
    float vv[4] = {v.x, v.y, v.z, v.w};
    uint4_t u;
    #pragma unroll
    for (int t = 0; t < 4; t++) {
      unsigned int bits = __float_as_uint(vv[t]);
      unsigned int hs = bits & 0xFFFF0000u;
      float hf = __uint_as_float(hs);
      unsigned int ls = __float_as_uint(vv[t] - hf) >> 16;
      u[t] = hs | ls;
    }
    int base = (ci * 11 + row) * 72 + c4 * 4;
    *(uint4_t*)&xshl[base] = u;
  }
  __syncthreads();

  auto conv1_tile = [&](int pt) {
    int r, c; bool pvalid;
    if (pt < 10) { r = pt >> 1; c = ((pt & 1) << 4) + m15; pvalid = true; }
    else { r = (m15 < 5) ? m15 : 0; c = 32; pvalid = (m15 < 5); }
    short8_t Xh = {}; short8_t Xl = {};
    #pragma unroll
    for (int j = 0; j < 8; j++) {
      int k = quad * 8 + j;
      int ci = (k * 57) >> 9;
      int rem = k - ci * 9;
      int ky = (rem * 11) >> 5;
      int kx = rem - ky * 3;
      int addr = (ci * 11 + 2 * r + ky) * 72 + 2 * c + kx;
      if (k < 27 && pvalid) {
        uint_t v = xshl[addr];
        Xh[j] = (short)(v >> 16);
        Xl[j] = (short)(v & 0xFFFFu);
      }
    }
    bool zf = (r == 4 && band == 15) || (c == 32 && h == 1);
    #pragma unroll
    for (int ct = 0; ct < 4; ct++) {
      short8_t Wh = *(const short8_t*)(w1bh + ((ct * 64 + lane) << 3));
      short8_t Wl = *(const short8_t*)(w1bl + ((ct * 64 + lane) << 3));
      f32x4 a1 = {0.f, 0.f, 0.f, 0.f};
      a1 = MFMA_BF16_16x16x32(Wh, Xh, a1, 0, 0, 0);
      a1 = MFMA_BF16_16x16x32(Wh, Xl, a1, 0, 0, 0);
      a1 = MFMA_BF16_16x16x32(Wl, Xh, a1, 0, 0, 0);
      if (pvalid) {
        short4_t hv, lv;
        #pragma unroll
        for (int reg = 0; reg < 4; reg++) {
          int co = ct * 16 + (quad << 2) + reg;
          float v = zf ? 0.f : fmaxf(a1[reg] + b1[co], 0.f);
          unsigned int bits = __float_as_uint(v);
          hv[reg] = (short)(bits >> 16);
          float hf = __uint_as_float(bits & 0xFFFF0000u);
          lv[reg] = (short)(__float_as_uint(v - hf) >> 16);
        }
        int be = F1IDX(r, c, ct * 16 + (quad << 2));
        *(short4_t*)&f1h[be] = hv;
        *(short4_t*)&f1l[be] = lv;
      }
    }
  };
  conv1_tile(wave);
  if (wave >= 4 && wave < 7) conv1_tile(8 + (wave - 4));
  __syncthreads();

  if (wave < 4) {
    int nt = wave;
    f32x4 acc0 = {0.f, 0.f, 0.f, 0.f};
    f32x4 acc1 = {0.f, 0.f, 0.f, 0.f};
    #pragma unroll
    for (int t = 0; t < 9; t++) {
      int ky = t / 3, kx = t % 3;
      int col = 2 * m15 + kx;
      #pragma unroll
      for (int q = 0; q < 2; q++) {
        int widx = (((t * 2 + q) * 4 + nt) * 64 + lane) * 8;
        short8_t Bh = *(const short8_t*)(w2fh + widx);
        short8_t Bl = *(const short8_t*)(w2fl + widx);
        {
          int ae = F1IDX(ky, col, q * 32 + (quad << 3));
          short8_t Ah = *(const short8_t*)&f1h[ae];
          short8_t Al = *(const short8_t*)&f1l[ae];
          acc0 = MFMA_BF16_16x16x32(Ah, Bh, acc0, 0, 0, 0);
          acc0 = MFMA_BF16_16x16x32(Ah, Bl, acc0, 0, 0, 0);
          acc0 = MFMA_BF16_16x16x32(Al, Bh, acc0, 0, 0, 0);
        }
        {
          int ae = F1IDX(2 + ky, col, q * 32 + (quad << 3));
          short8_t Ah = *(const short8_t*)&f1h[ae];
          short8_t Al = *(const short8_t*)&f1l[ae];
          acc1 = MFMA_BF16_16x16x32(Ah, Bh, acc1, 0, 0, 0);
          acc1 = MFMA_BF16_16x16x32(Ah, Bl, acc1, 0, 0, 0);
          acc1 = MFMA_BF16_16x16x32(Al, Bh, acc1, 0, 0, 0);
        }
      }
    }
    int co = nt * 16 + m15;
    float bv = b2[co];
    int ox = h * 16 + (quad << 2);
    {
      int oy = band * 2;
      float4 o;
      o.x = fmaxf(acc0[0] + bv, 0.f);
      o.y = fmaxf(acc0[1] + bv, 0.f);
      o.z = fmaxf(acc0[2] + bv, 0.f);
      o.w = fmaxf(acc0[3] + bv, 0.f);
      *(float4*)&feat2[((n * 64 + co) * 32 + oy) * 32 + ox] = o;
    }
    {
      int oy = band * 2 + 1;
      float4 o;
      o.x = fmaxf(acc1[0] + bv, 0.f);
      o.y = fmaxf(acc1[1] + bv, 0.f);
      o.z = fmaxf(acc1[2] + bv, 0.f);
      o.w = fmaxf(acc1[3] + bv, 0.f);
      *(float4*)&feat2[((n * 64 + co) * 32 + oy) * 32 + ox] = o;
    }
  }
}

// ---- merged head: ROI-align+fc0 GEMM (bx<192) | emb+fc1c GEMM (bx>=192) ----
__global__ __launch_bounds__(512) void headgemm_kernel(const float* __restrict__ feat2,
                                                       const float* __restrict__ rois,
                                                       const float* __restrict__ fc0T,
                                                       const float* __restrict__ fc0_b,
                                                       const float* __restrict__ src_coor,
                                                       const float* __restrict__ w0,
                                                       const float* __restrict__ b0,
                                                       const float* __restrict__ fc1cT,
                                                       const float* __restrict__ b1c,
                                                       float* __restrict__ cat) {
  __shared__ __align__(16) float As[8 * 1024];
  int tid = threadIdx.x;
  int bx = blockIdx.x;
  if (bx < 192) {
    int r0 = bx * 8;
    for (int idx = tid; idx < 8192; idx += 512) {
      int px = idx & 3, py = (idx >> 2) & 3, c = (idx >> 4) & 63, rr = idx >> 10;
      const float* rp = rois + (size_t)(r0 + rr) * 5;
      int bi = (int)rp[0];
      float x1 = rp[1] * 0.25f, y1 = rp[2] * 0.25f, x2 = rp[3] * 0.25f, y2 = rp[4] * 0.25f;
      float bw = fmaxf(x2 - x1, 1.0f) * 0.25f;
      float bh = fmaxf(y2 - y1, 1.0f) * 0.25f;
      float sx = x1 + bw * (px + 0.5f);
      float sy = y1 + bh * (py + 0.5f);
      float x0f = fminf(fmaxf(floorf(sx), 0.f), 31.f);
      float y0f = fminf(fmaxf(floorf(sy), 0.f), 31.f);
      float lx = fminf(fmaxf(sx - x0f, 0.f), 1.f);
      float ly = fminf(fmaxf(sy - y0f, 0.f), 1.f);
      int ix0 = (int)x0f, iy0 = (int)y0f;
      int ix1 = min(ix0 + 1, 31), iy1 = min(iy0 + 1, 31);
      const float* f = feat2 + (bi * 64 + c) * 1024;
      float v00 = f[iy0 * 32 + ix0], v01 = f[iy0 * 32 + ix1];
      float v10 = f[iy1 * 32 + ix0], v11 = f[iy1 * 32 + ix1];
      As[idx] = v00 * (1 - ly) * (1 - lx) + v01 * (1 - ly) * lx + v10 * ly * (1 - lx) +
                v11 * ly * lx;
    }
    __syncthreads();
    int d = tid & 255;
    int half = __builtin_amdgcn_readfirstlane(tid >> 8);
    float acc[4] = {};
    const float* asb = As + half * 4 * 1024;
    for (int kq = 0; kq < 256; kq++) {
      float4 wv = *(const float4*)(fc0T + kq * 1024 + d * 4);
      #pragma unroll
      for (int rr = 0; rr < 4; rr++) {
        float4 a4 = *(const float4*)(asb + rr * 1024 + kq * 4);
        FMA4(acc[rr], a4, wv);
      }
    }
    float bv = fc0_b[d];
    #pragma unroll
    for (int rr = 0; rr < 4; rr++)
      cat[(r0 + half * 4 + rr) * 512 + d] = fmaxf(acc[rr] + bv, 0.f);
  } else {
    int r0 = (bx - 192) * 8;
    for (int idx = tid; idx < 2048; idx += 512) {
      int rr = idx >> 8, c = idx & 255;
      const float* cp = src_coor + (size_t)(r0 + rr) * 2;
      float v = cp[0] * w0[c * 2] + cp[1] * w0[c * 2 + 1] + b0[c];
      As[idx] = fmaxf(v, 0.f);
    }
    __syncthreads();
    int d = tid & 255;
    int half = __builtin_amdgcn_readfirstlane(tid >> 8);
    float acc[4] = {};
    const float* asb = As + half * 4 * 256;
    for (int kq = 0; kq < 64; kq++) {
      float4 wv = *(const float4*)(fc1cT + kq * 1024 + d * 4);
      #pragma unroll
      for (int rr = 0; rr < 4; rr++) {
        float4 a4 = *(const float4*)(asb + rr * 256 + kq * 4);
        FMA4(acc[rr], a4, wv);
      }
    }
    float bv = b1c[d];
    #pragma unroll
    for (int rr = 0; rr < 4; rr++)
      cat[(r0 + half * 4 + rr) * 512 + 256 + d] = fmaxf(acc[rr] + bv, 0.f);
  }
}

// ---- generic broadcast-row GEMM + bias + relu ----
__global__ __launch_bounds__(512) void gemmB_kernel(const float* __restrict__ A, int lda,
                                                    const float* __restrict__ WT,
                                                    const float* __restrict__ bias,
                                                    float* __restrict__ C, int ldc, int coff,
                                                    int kshift) {
  __shared__ __align__(16) float As[8 * 1024];
  int K = 1 << kshift;
  int tid = threadIdx.x;
  int r0 = blockIdx.x * 8;
  for (int idx = tid; idx < 8 * K; idx += 512)
    As[idx] = A[(r0 + (idx >> kshift)) * lda + (idx & (K - 1))];
  __syncthreads();
  int d = tid & 255;
  int half = __builtin_amdgcn_readfirstlane(tid >> 8);
  float acc[4] = {};
  const float* asb = As + half * 4 * K;
  for (int kq = 0; kq < (K >> 2); kq++) {
    float4 wv = *(const float4*)(WT + kq * 1024 + d * 4);
    #pragma unroll
    for (int rr = 0; rr < 4; rr++) {
      float4 a4 = *(const float4*)(asb + rr * K + kq * 4);
      FMA4(acc[rr], a4, wv);
    }
  }
  float bv = bias[d];
  #pragma unroll
  for (int rr = 0; rr < 4; rr++)
    C[(r0 + half * 4 + rr) * ldc + coff + d] = fmaxf(acc[rr] + bv, 0.f);
}

// ---- internet via MFMA: 128 blocks = (k-XCD-pair, b-pair). M=12 (2 batches), 16 waves. ----
// round-12 version: 2-deep in-loop software pipelining of B-fragment loads.
__global__ __launch_bounds__(1024, 4) void internet_mfma(
    int j, const float* __restrict__ obj, float* __restrict__ spart,
    const float* __restrict__ src_coor, float* __restrict__ dout,
    const float* __restrict__ rbuf,
    const ushort_t* __restrict__ b1h, const ushort_t* __restrict__ b1l,
    const ushort_t* __restrict__ bafh, const ushort_t* __restrict__ bafl,
    const ushort_t* __restrict__ bouh, const ushort_t* __restrict__ boul,
    const ushort_t* __restrict__ bagh, const ushort_t* __restrict__ bagl,
    const float* __restrict__ self_b, const float* __restrict__ rel_b,
    const float* __restrict__ aff_b, const float* __restrict__ out_b,
    const float* __restrict__ agg_b,
    const float* __restrict__ decw, const float* __restrict__ decb) {
  __shared__ __align__(16) char smem[62784];
  __shared__ float coor_lds[2][12], r_lds[2][6], mw[2][6][8];
  float* bufA = (float*)smem;
  ushort_t* sAh = (ushort_t*)(smem + 37440);
  ushort_t* sAl = (ushort_t*)(smem + 43776);
  ushort_t* hAh = (ushort_t*)(smem + 50112);
  ushort_t* hAl = (ushort_t*)(smem + 56448);
  ushort_t* aAh = (ushort_t*)(smem);
  ushort_t* aAl = (ushort_t*)(smem + 6336);
  ushort_t* csAh = hAh;
  ushort_t* csAl = hAl;

  int bx = blockIdx.x;
  int k = __builtin_amdgcn_readfirstlane((bx & 7) >> 1);
  int pb = __builtin_amdgcn_readfirstlane(((bx & 1) << 4) | (bx >> 3));   // 0..31
  int tid = threadIdx.x;
  int wave = __builtin_amdgcn_readfirstlane(tid >> 6);   // 0..15
  int lane = tid & 63;
  int m15 = lane & 15, quad = lane >> 4;
  int mrow = (m15 < 12) ? m15 : 0;
  int sl = j + k;
  bool dodec = (k == 3) && (j >= 1);

  const ushort_t* b1hk = b1h + (size_t)k * 196608;
  const ushort_t* b1lk = b1l + (size_t)k * 196608;
  const ushort_t* bafhk = bafh + (size_t)k * 65536;
  const ushort_t* baflk = bafl + (size_t)k * 65536;
  const ushort_t* bouhk = bouh + (size_t)k * 131072;
  const ushort_t* boulk = boul + (size_t)k * 131072;
  const ushort_t* baghk = bagh + (size_t)k * 65536;
  const ushort_t* baglk = bagl + (size_t)k * 65536;

  // prefetch P1 kq=0 B-fragments: they land during P0's global s staging + barrier
  short8_t p1Bh[2][3], p1Bl[2][3];
  #pragma unroll
  for (int tt = 0; tt < 3; tt++) {
    int t = wave * 3 + tt;
    int bi = ((t * 8 + 0) * 64 + lane) * 8;
    p1Bh[0][tt] = *(const short8_t*)(b1hk + bi);
    p1Bl[0][tt] = *(const short8_t*)(b1lk + bi);
  }

  // P0a: r / coor / stage s (12x256): fp32 -> bufA[0..3071], bf16 split -> sA
  if (tid < 12) r_lds[tid / 6][tid % 6] = rbuf[(pb * 2 + tid / 6) * 6 + tid % 6];
  if (!dodec && tid < 24) {
    int bq = tid / 12, t12 = tid % 12;
    int i = t12 >> 1, c = t12 & 1;
    int b = pb * 2 + bq;
    coor_lds[bq][t12] = (sl < 4) ? src_coor[((b * 4 + sl) * 6 + i) * 2 + c]
                                 : dout[((b * 8 + (sl - 4)) * 6 + i) * 4 + 2 + c];
  }
  {
    size_t pbase = ((size_t)(sl - 4) * 4) * 64;
    for (int pos = tid; pos < 3072; pos += 1024) {
      int row = pos >> 8, d = pos & 255;
      int bq = row >= 6, i = row - bq * 6;
      int b = pb * 2 + bq;
      float v;
      if (sl < 4) {
        v = obj[(b * 4 + sl) * 1536 + i * 256 + d];
      } else {
        size_t eo = (size_t)i * 256 + d;
        v = agg_b[d]
          + spart[(pbase +   0 + b) * 1536 + eo]
          + spart[(pbase +  64 + b) * 1536 + eo]
          + spart[(pbase + 128 + b) * 1536 + eo]
          + spart[(pbase + 192 + b) * 1536 + eo];
      }
      bufA[pos] = v;
      ushort_t hs, ls;
      split_bf16(v, hs, ls);
      sAh[row * 264 + d] = hs;
      sAl[row * 264 + d] = ls;
    }
  }
  __syncthreads();

  // P0b: dec for rollout j-1 (k==3), reading fp32 s from bufA
  if (dodec && tid < 384) {
    int lane8 = tid & 7, p = tid >> 3;   // 0..47
    int bq = p / 24, pp = p % 24, i = pp >> 2, o = pp & 3;
    float a2 = 0.f;
    #pragma unroll
    for (int m = 0; m < 32; m++) {
      int dd = lane8 + m * 8;
      a2 = fmaf(bufA[(bq * 6 + i) * 256 + dd], decw[o * 256 + dd], a2);
    }
    a2 += __shfl_down(a2, 4, 8);
    a2 += __shfl_down(a2, 2, 8);
    a2 += __shfl_down(a2, 1, 8);
    if (lane8 == 0) {
      float val = a2 + decb[o];
      int b = pb * 2 + bq;
      dout[((b * 8 + (j - 1)) * 6 + i) * 4 + o] = val;
      if (o >= 2) coor_lds[bq][i * 2 + (o - 2)] = val;
    }
  }
  __syncthreads();

  // P1: mask + stage-1 MFMA (48 tiles, 3/wave) with 2-deep B ring
  #pragma unroll
  for (int tt = 0; tt < 3; tt++) {
    int t = wave * 3 + tt;
    int bi = ((t * 8 + 1) * 64 + lane) * 8;
    p1Bh[1][tt] = *(const short8_t*)(b1hk + bi);
    p1Bl[1][tt] = *(const short8_t*)(b1lk + bi);
  }
  if (tid < 72) {
    int bq = tid / 36, rest = tid % 36;
    int i = rest / 6, jj = rest % 6;
    float dx = coor_lds[bq][i * 2] - coor_lds[bq][jj * 2];
    float dy = coor_lds[bq][i * 2 + 1] - coor_lds[bq][jj * 2 + 1];
    float dist = sqrtf(dx * dx + dy * dy);
    mw[bq][i][jj] = (i != jj && dist <= r_lds[bq][i] + r_lds[bq][jj]) ? 1.f : 0.f;
  }
  {
    f32x4 acc1[3] = {};
    #pragma unroll
    for (int kq = 0; kq < 8; kq++) {
      int cur = kq & 1;
      int aoff = mrow * 264 + kq * 32 + quad * 8;
      short8_t Ah = *(const short8_t*)(sAh + aoff);
      short8_t Al = *(const short8_t*)(sAl + aoff);
      #pragma unroll
      for (int tt = 0; tt < 3; tt++) {
        acc1[tt] = MFMA_BF16_16x16x32(Ah, p1Bh[cur][tt], acc1[tt], 0, 0, 0);
        acc1[tt] = MFMA_BF16_16x16x32(Ah, p1Bl[cur][tt], acc1[tt], 0, 0, 0);
        acc1[tt] = MFMA_BF16_16x16x32(Al, p1Bh[cur][tt], acc1[tt], 0, 0, 0);
      }
      if (kq < 6) {
        #pragma unroll
        for (int tt = 0; tt < 3; tt++) {
          int t = wave * 3 + tt;
          int bi = ((t * 8 + kq + 2) * 64 + lane) * 8;
          p1Bh[cur][tt] = *(const short8_t*)(b1hk + bi);
          p1Bl[cur][tt] = *(const short8_t*)(b1lk + bi);
        }
      }
    }
    #pragma unroll
    for (int tt = 0; tt < 3; tt++) {
      int t = wave * 3 + tt;
      int mat = t >> 4, ntm = t & 15;
      float* buf = bufA + mat * 3120;
      #pragma unroll
      for (int reg = 0; reg < 4; reg++) {
        int m = quad * 4 + reg;
        if (m < 12) buf[m * 260 + ntm * 16 + m15] = acc1[tt][reg];
      }
    }
  }
  __syncthreads();

  // P2: h = as + self_b + cnt*(au+rel_b) + sum_j mw*av ; repack -> hA
  for (int pos = tid; pos < 3072; pos += 1024) {
    int row = pos >> 8, d = pos & 255;
    int bq = row >= 6, i = row - bq * 6;
    float as = bufA[row * 260 + d];
    float au = bufA[3120 + row * 260 + d];
    float cw = mw[bq][i][0] + mw[bq][i][1] + mw[bq][i][2] + mw[bq][i][3] + mw[bq][i][4] +
               mw[bq][i][5];
    float hsum = as + self_b[k * 256 + d] + cw * (au + rel_b[k * 256 + d]);
    #pragma unroll
    for (int jj = 0; jj < 6; jj++)
      hsum = fmaf(mw[bq][i][jj], bufA[6240 + (bq * 6 + jj) * 260 + d], hsum);
    ushort_t hs, ls;
    split_bf16(hsum, hs, ls);
    hAh[row * 264 + d] = hs;
    hAl[row * 264 + d] = ls;
  }
  // prefetch P3 kq 0..3 B-fragments: land during the barrier drain
  short8_t p3Bh[4], p3Bl[4];
  #pragma unroll
  for (int kq = 0; kq < 4; kq++) {
    int bi = ((wave * 8 + kq) * 64 + lane) * 8;
    p3Bh[kq] = *(const short8_t*)(bafhk + bi);
    p3Bl[kq] = *(const short8_t*)(baflk + bi);
  }
  __syncthreads();

  // P3: aff MFMA (16 tiles, 1/wave) -> relu -> aA (aliased over bufA)
  short8_t p4Bh[4], p4Bl[4];
  {
    short8_t r3h[2], r3l[2];
    #pragma unroll
    for (int q = 0; q < 2; q++) {
      int bi = ((wave * 8 + 4 + q) * 64 + lane) * 8;
      r3h[q] = *(const short8_t*)(bafhk + bi);
      r3l[q] = *(const short8_t*)(baflk + bi);
    }
    f32x4 acc2 = {0.f, 0.f, 0.f, 0.f};
    #pragma unroll
    for (int kq = 0; kq < 4; kq++) {
      int aoff = mrow * 264 + kq * 32 + quad * 8;
      short8_t Ah = *(const short8_t*)(hAh + aoff);
      short8_t Al = *(const short8_t*)(hAl + aoff);
      acc2 = MFMA_BF16_16x16x32(Ah, p3Bh[kq], acc2, 0, 0, 0);
      acc2 = MFMA_BF16_16x16x32(Ah, p3Bl[kq], acc2, 0, 0, 0);
      acc2 = MFMA_BF16_16x16x32(Al, p3Bh[kq], acc2, 0, 0, 0);
    }
    #pragma unroll
    for (int kq = 4; kq < 8; kq++) {
      int cur = kq & 1;
      int aoff = mrow * 264 + kq * 32 + quad * 8;
      short8_t Ah = *(const short8_t*)(hAh + aoff);
      short8_t Al = *(const short8_t*)(hAl + aoff);
      acc2 = MFMA_BF16_16x16x32(Ah, r3h[cur], acc2, 0, 0, 0);
      acc2 = MFMA_BF16_16x16x32(Ah, r3l[cur], acc2, 0, 0, 0);
      acc2 = MFMA_BF16_16x16x32(Al, r3h[cur], acc2, 0, 0, 0);
      if (kq < 6) {
        int bi = ((wave * 8 + kq + 2) * 64 + lane) * 8;
        r3h[cur] = *(const short8_t*)(bafhk + bi);
        r3l[cur] = *(const short8_t*)(baflk + bi);
      }
    }
    #pragma unroll
    for (int kq = 0; kq < 4; kq++) {
      int bi = ((wave * 16 + kq) * 64 + lane) * 8;
      p4Bh[kq] = *(const short8_t*)(bouhk + bi);
      p4Bl[kq] = *(const short8_t*)(boulk + bi);
    }
    __syncthreads();   // bufA fully read in P2; safe to overwrite with aA
    int d = wave * 16 + m15;
    float bias = aff_b[k * 256 + d];
    #pragma unroll
    for (int reg = 0; reg < 4; reg++) {
      int m = quad * 4 + reg;
      if (m < 12) {
        float v = fmaxf(acc2[reg] + bias, 0.f);
        ushort_t hs, ls;
        split_bf16(v, hs, ls);
        aAh[m * 264 + d] = hs;
        aAl[m * 264 + d] = ls;
      }
    }
  }
  __syncthreads();

  // P4: out MFMA over K=512 ([a|s], 16 tiles, 1/wave) -> relu -> csA (LDS k-slice of cs)
  short8_t p5Bh[4], p5Bl[4];
  {
    short8_t r4h[2], r4l[2];
    #pragma unroll
    for (int q = 0; q < 2; q++) {
      int bi = ((wave * 16 + 4 + q) * 64 + lane) * 8;
      r4h[q] = *(const short8_t*)(bouhk + bi);
      r4l[q] = *(const short8_t*)(boulk + bi);
    }
    f32x4 acc3 = {0.f, 0.f, 0.f, 0.f};
    #pragma unroll
    for (int kq = 0; kq < 4; kq++) {
      const ushort_t* Abh = aAh + mrow * 264 + kq * 32;
      const ushort_t* Abl = aAl + mrow * 264 + kq * 32;
      short8_t Ah = *(const short8_t*)(Abh + quad * 8);
      short8_t Al = *(const short8_t*)(Abl + quad * 8);
      acc3 = MFMA_BF16_16x16x32(Ah, p4Bh[kq], acc3, 0, 0, 0);
      acc3 = MFMA_BF16_16x16x32(Ah, p4Bl[kq], acc3, 0, 0, 0);
      acc3 = MFMA_BF16_16x16x32(Al, p4Bh[kq], acc3, 0, 0, 0);
    }
    #pragma unroll
    for (int kq = 4; kq < 16; kq++) {
      int cur = kq & 1;
      const ushort_t* Abh = (kq < 8) ? (aAh + mrow * 264 + kq * 32)
                                     : (sAh + mrow * 264 + (kq - 8) * 32);
      const ushort_t* Abl = (kq < 8) ? (aAl + mrow * 264 + kq * 32)
                                     : (sAl + mrow * 264 + (kq - 8) * 32);
      short8_t Ah = *(const short8_t*)(Abh + quad * 8);
      short8_t Al = *(const short8_t*)(Abl + quad * 8);
      acc3 = MFMA_BF16_16x16x32(Ah, r4h[cur], acc3, 0, 0, 0);
      acc3 = MFMA_BF16_16x16x32(Ah, r4l[cur], acc3, 0, 0, 0);
      acc3 = MFMA_BF16_16x16x32(Al, r4h[cur], acc3, 0, 0, 0);
      if (kq < 14) {
        int bi = ((wave * 16 + kq + 2) * 64 + lane) * 8;
        r4h[cur] = *(const short8_t*)(bouhk + bi);
        r4l[cur] = *(const short8_t*)(boulk + bi);
      }
    }
    #pragma unroll
    for (int kq = 0; kq < 4; kq++) {
      int bi = ((wave * 8 + kq) * 64 + lane) * 8;
      p5Bh[kq] = *(const short8_t*)(baghk + bi);
      p5Bl[kq] = *(const short8_t*)(baglk + bi);
    }
    // hA dead after P3 -> write relu'd cs k-slice there (P4 reads only aA/sA).
    int d = wave * 16 + m15;
    float bias = out_b[k * 256 + d];
    #pragma unroll
    for (int reg = 0; reg < 4; reg++) {
      int m = quad * 4 + reg;
      if (m < 12) {
        float v = fmaxf(acc3[reg] + bias, 0.f);
        ushort_t hs, ls;
        split_bf16(v, hs, ls);
        csAh[m * 264 + d] = hs;
        csAl[m * 264 + d] = ls;
      }
    }
  }
  __syncthreads();

  // P5: partial agg spart[j][k][b] = cs_slice @ aggW[:, k*256:(k+1)*256]^T (M=12,N=256,K=256)
  {
    short8_t r5h[2], r5l[2];
    #pragma unroll
    for (int q = 0; q < 2; q++) {
      int bi = ((wave * 8 + 4 + q) * 64 + lane) * 8;
      r5h[q] = *(const short8_t*)(baghk + bi);
      r5l[q] = *(const short8_t*)(baglk + bi);
    }
    f32x4 pacc = {0.f, 0.f, 0.f, 0.f};
    #pragma unroll
    for (int kq = 0; kq < 4; kq++) {
      int aoff = mrow * 264 + kq * 32 + quad * 8;
      short8_t Ah = *(const short8_t*)(csAh + aoff);
      short8_t Al = *(const short8_t*)(csAl + aoff);
      pacc = MFMA_BF16_16x16x32(Ah, p5Bh[kq], pacc, 0, 0, 0);
      pacc = MFMA_BF16_16x16x32(Ah, p5Bl[kq], pacc, 0, 0, 0);
      pacc = MFMA_BF16_16x16x32(Al, p5Bh[kq], pacc, 0, 0, 0);
    }
    #pragma unroll
    for (int kq = 4; kq < 8; kq++) {
      int cur = kq & 1;
      int aoff = mrow * 264 + kq * 32 + quad * 8;
      short8_t Ah = *(const short8_t*)(csAh + aoff);
      short8_t Al = *(const short8_t*)(csAl + aoff);
      pacc = MFMA_BF16_16x16x32(Ah, r5h[cur], pacc, 0, 0, 0);
      pacc = MFMA_BF16_16x16x32(Ah, r5l[cur], pacc, 0, 0, 0);
      pacc = MFMA_BF16_16x16x32(Al, r5h[cur], pacc, 0, 0, 0);
      if (kq < 6) {
        int bi = ((wave * 8 + kq + 2) * 64 + lane) * 8;
        r5h[cur] = *(const short8_t*)(baghk + bi);
        r5l[cur] = *(const short8_t*)(baglk + bi);
      }
    }
    int d = wave * 16 + m15;
    #pragma unroll
    for (int reg = 0; reg < 4; reg++) {
      int m = quad * 4 + reg;
      if (m < 12) {
        int bq = m >= 6, i = m - bq * 6;
        int b = pb * 2 + bq;
        spart[(((size_t)j * 4 + k) * 64 + b) * 1536 + i * 256 + d] = pacc[reg];
      }
    }
  }
}

// ---- final dec for rollout 7 (sums the 4 agg partials + agg_b) ----
__global__ void dec_last(const float* __restrict__ spart, const float* __restrict__ agg_b,
                         const float* __restrict__ decw, const float* __restrict__ decb,
                         float* __restrict__ dout) {
  int b = blockIdx.x;
  int tid = threadIdx.x;   // 384
  int lane16 = tid & 15;
  int p = tid >> 4;
  int i = p >> 2, o = p & 3;
  const float* p0 = spart + ((size_t)(7 * 4 + 0) * 64 + b) * 1536 + i * 256;
  const float* p1 = spart + ((size_t)(7 * 4 + 1) * 64 + b) * 1536 + i * 256;
  const float* p2 = spart + ((size_t)(7 * 4 + 2) * 64 + b) * 1536 + i * 256;
  const float* p3 = spart + ((size_t)(7 * 4 + 3) * 64 + b) * 1536 + i * 256;
  float a2 = 0.f;
  #pragma unroll
  for (int m = 0; m < 16; m++) {
    int dd = lane16 + m * 16;
    float sv = agg_b[dd] + p0[dd] + p1[dd] + p2[dd] + p3[dd];
    a2 = fmaf(sv, decw[o * 256 + dd], a2);
  }
  a2 += __shfl_down(a2, 8, 16);
  a2 += __shfl_down(a2, 4, 16);
  a2 += __shfl_down(a2, 2, 16);
  a2 += __shfl_down(a2, 1, 16);
  if (lane16 == 0) dout[((b * 8 + 7) * 6 + i) * 4 + o] = a2 + decb[o];
}

extern "C" void kernel_launch(void* const* d_in, const int* in_sizes, int n_in,
                              void* d_out, int out_size, void* d_ws, size_t ws_size,
                              hipStream_t stream) {
  const float* x        = (const float*)d_in[0];
  const float* rois     = (const float*)d_in[1];
  const float* src_coor = (const float*)d_in[2];
  const float* w_conv1  = (const float*)d_in[3];
  const float* b_conv1  = (const float*)d_in[4];
  const float* w_conv2  = (const float*)d_in[5];
  const float* b_conv2  = (const float*)d_in[6];
  const float* fc0_w    = (const float*)d_in[7];
  const float* fc0_b    = (const float*)d_in[8];
  const float* fc0c_w   = (const float*)d_in[9];
  const float* fc0c_b   = (const float*)d_in[10];
  const float* fc1c_w   = (const float*)d_in[11];
  const float* fc1c_b   = (const float*)d_in[12];
  const float* red_w    = (const float*)d_in[13];
  const float* red_b    = (const float*)d_in[14];
  const float* g_self_w = (const float*)d_in[15];
  const float* g_self_b = (const float*)d_in[16];
  const float* g_rel_w  = (const float*)d_in[17];
  const float* g_rel_b  = (const float*)d_in[18];
  const float* g_aff_w  = (const float*)d_in[19];
  const float* g_aff_b  = (const float*)d_in[20];
  const float* g_out_w  = (const float*)d_in[21];
  const float* g_out_b  = (const float*)d_in[22];
  const float* agg_w    = (const float*)d_in[23];
  const float* agg_b    = (const float*)d_in[24];
  const float* dec_w    = (const float*)d_in[25];
  const float* dec_b    = (const float*)d_in[26];
  float* out = (float*)d_out;

  float* ws = (float*)d_ws;
  size_t off = 0;
  auto alloc = [&](size_t nf) { float* p = ws + off; off += (nf + 63) & ~(size_t)63; return p; };
  float* feat2 = alloc(16777216);   // (256,64,32,32)
  float* cat   = alloc(786432);
  float* obj   = alloc(393216);
  float* spart = alloc(3145728);    // [8 slots][4 k][64 b][6][256] agg partials
  float* rbuf  = alloc(384);
  float* fc0T  = alloc(262144);
  float* fc1cT = alloc(65536);
  float* redT  = alloc(131072);
  ushort_t* w1bh = (ushort_t*)alloc(1024);
  ushort_t* w1bl = (ushort_t*)alloc(1024);
  ushort_t* w2fh = (ushort_t*)alloc(18432);
  ushort_t* w2fl = (ushort_t*)alloc(18432);
  ushort_t* b1h  = (ushort_t*)alloc(393216);   // 4k x 196608 shorts
  ushort_t* b1l  = (ushort_t*)alloc(393216);
  ushort_t* bafh = (ushort_t*)alloc(131072);   // 4k x 65536 shorts
  ushort_t* bafl = (ushort_t*)alloc(131072);
  ushort_t* bouh = (ushort_t*)alloc(262144);   // 4k x 131072 shorts
  ushort_t* boul = (ushort_t*)alloc(262144);
  ushort_t* bagh = (ushort_t*)alloc(131072);   // 4k x 65536 shorts (per-k agg slices)
  ushort_t* bagl = (ushort_t*)alloc(131072);

  MatDescs md;
  md.m[0] = {fc0_w,  fc0T,  10, 1024, 0};
  md.m[1] = {fc1c_w, fc1cT, 8,  256,  0};
  md.m[2] = {red_w,  redT,  9,  512,  0};
  md.m[3] = {red_w,  redT,  9,  512,  0};   // unused

  prep_small<<<dim3(154), dim3(256), 0, stream>>>(w_conv1, w_conv2, rois, w1bh, w1bl,
                                                  w2fh, w2fl, rbuf);
  // mega: convmf (8192) + prep_rollB (3584) + prep_mats (896)
  convprep_kernel<<<dim3(12672), dim3(512), 0, stream>>>(
      x, w1bh, w1bl, b_conv1, w2fh, w2fl, b_conv2, feat2,
      g_self_w, g_rel_w, g_aff_w, g_out_w, agg_w,
      b1h, b1l, bafh, bafl, bouh, boul, bagh, bagl, md);
  headgemm_kernel<<<dim3(384), dim3(512), 0, stream>>>(feat2, rois, fc0T, fc0_b,
                                                       src_coor, fc0c_w, fc0c_b,
                                                       fc1cT, fc1c_b, cat);
  gemmB_kernel<<<dim3(192), dim3(512), 0, stream>>>(cat, 512, redT, red_b, obj, 256, 0, 9);

  for (int j = 0; j < 8; j++) {
    internet_mfma<<<dim3(128), dim3(1024), 0, stream>>>(j, obj, spart, src_coor, out, rbuf,
        b1h, b1l, bafh, bafl, bouh, boul, bagh, bagl,
        g_self_b, g_rel_b, g_aff_b, g_out_b, agg_b, dec_w, dec_b);
  }
  dec_last<<<dim3(64), dim3(384), 0, stream>>>(spart, agg_b, dec_w, dec_b, out);

  (void)in_sizes; (void)n_in; (void)out_size; (void)ws_size;
}